// Round 10
// baseline (54.013 us; speedup 1.0000x reference)
//
#include <hip/hip_runtime.h>

#define B_ 2
#define L_ 256
#define H_ 256
#define A_ 32
#define P_ 64

typedef __bf16 bf16x8 __attribute__((ext_vector_type(8)));
typedef __bf16 bf16x4 __attribute__((ext_vector_type(4)));
typedef float  f32x4  __attribute__((ext_vector_type(4)));

// k1: h ONLY (g moved into k2). 256 blocks x 2 rows; 4 threads per 256-dot.
// Writes h as f32 (for k2's f32 g-compute) and bf16 (MFMA B-operand).
__global__ __launch_bounds__(256) void k1_h(
    const float* __restrict__ x,     // [B,L,H]
    const float* __restrict__ in_w,  // [A,H]
    const float* __restrict__ in_b,  // [A]
    float* __restrict__ hf,          // [B*L][A] f32
    __bf16* __restrict__ hb)         // [B*L][A] bf16
{
    __shared__ float xs[2 * H_];
    const int t = threadIdx.x;
    const int r0 = blockIdx.x * 2;

    if (t < 128) ((float4*)xs)[t] = ((const float4*)(x + (size_t)r0 * H_))[t];
    __syncthreads();

    const int jj = t >> 7;        // row 0..1
    const int rem = t & 127;
    const int a = rem >> 2;       // 0..31
    const int q = rem & 3;        // quarter of the 256-dot
    const float4* w4 = (const float4*)(in_w + a * H_ + q * 64);
    const float4* xv4 = (const float4*)(xs + jj * H_ + q * 64);
    float s = 0.f;
    #pragma unroll
    for (int m = 0; m < 16; ++m) {
        float4 w = w4[m], xv = xv4[m];
        s += w.x * xv.x + w.y * xv.y + w.z * xv.z + w.w * xv.w;
    }
    s += __shfl_xor(s, 1);
    s += __shfl_xor(s, 2);
    if (q == 0) {
        const float hv = s + in_b[a];
        hf[(size_t)(r0 + jj) * A_ + a] = hv;
        hb[(size_t)(r0 + jj) * A_ + a] = (__bf16)hv;
    }
}

// k2: fully fused. Block = (jt: 8 j's, ph: 32 p's, ih: 128 i's, b). 256 blocks.
// Phase 1: g[j][a][p-slice] computed in f32 from hf (zero redundancy: i unsplit
// within slice), rounded bf16 into LDS gt[j][kch][p][e] (a = kch*8+e).
// Phase 2: per i-tile: mfma(A=g, B=h) -> D[m=p][n=i]; acc+posT staged in LDS,
// linear NT readout in 64B-aligned runs.
__global__ __launch_bounds__(256) void k2_fused(
    const float* __restrict__ hf,    // [B*L][A] f32
    const __bf16* __restrict__ hb,   // [B*L][A] bf16
    const float* __restrict__ out_w, // [P, A*A]
    const float* __restrict__ out_b, // [P]
    const float* __restrict__ pos_w, // [P,17]
    const float* __restrict__ pos_b, // [P]
    float* __restrict__ out)         // [B,L,L,P]
{
    __shared__ float hj[8][A_];                        // h (f32) for the 8 j's
    __shared__ __align__(16) __bf16 gt[8][4][32][8];   // g bf16 [j][kch][p][e]
    __shared__ float posTl[17][36];                    // fused pos+biases, p-slice
    __shared__ float tile[16 * 292];                   // epilogue: i-stride 292, j-stride 36

    const int t = threadIdx.x;
    const int jt = blockIdx.x;        // 0..31
    const int ph = blockIdx.y >> 1;   // p-half 0..1
    const int ih = blockIdx.y & 1;    // i-half 0..1
    const int b  = blockIdx.z;
    const int j0 = jt * 8;
    const int p0 = ph * 32;
    const int ibase = ih * 128;

    // ---- phase 0: stage h_j + posT slice ----
    {
        const int j = t >> 5, a = t & 31;
        hj[j][a] = hf[((size_t)(b * L_ + j0 + j)) * A_ + a];
    }
    for (int e = t; e < 17 * 32; e += 256) {
        const int d = e >> 5, pp = e & 31;
        posTl[d][pp] = pos_w[(p0 + pp) * 17 + d] + pos_b[p0 + pp] + out_b[p0 + pp];
    }
    __syncthreads();

    // ---- phase 1: g-slice in f32, round to bf16 LDS ----
    {
        const int p = t & 31;         // local p
        const int ao = t >> 5;        // 0..7 -> a = ao*4 + aa
        float4 wv[4][8];
        #pragma unroll
        for (int aa = 0; aa < 4; ++aa) {
            const float4* wr = (const float4*)(out_w + (size_t)(p0 + p) * (A_ * A_) + (ao * 4 + aa) * A_);
            #pragma unroll
            for (int m = 0; m < 8; ++m) wv[aa][m] = wr[m];
        }
        const int kch = ao >> 1;
        const int eb = (ao & 1) * 4;
        #pragma unroll
        for (int j = 0; j < 8; ++j) {
            float s0 = 0.f, s1 = 0.f, s2 = 0.f, s3 = 0.f;
            #pragma unroll
            for (int m = 0; m < 8; ++m) {
                const float4 h4 = *(const float4*)&hj[j][m * 4];  // uniform -> broadcast
                s0 += wv[0][m].x * h4.x + wv[0][m].y * h4.y + wv[0][m].z * h4.z + wv[0][m].w * h4.w;
                s1 += wv[1][m].x * h4.x + wv[1][m].y * h4.y + wv[1][m].z * h4.z + wv[1][m].w * h4.w;
                s2 += wv[2][m].x * h4.x + wv[2][m].y * h4.y + wv[2][m].z * h4.z + wv[2][m].w * h4.w;
                s3 += wv[3][m].x * h4.x + wv[3][m].y * h4.y + wv[3][m].z * h4.z + wv[3][m].w * h4.w;
            }
            bf16x4 v;
            v[0] = (__bf16)s0; v[1] = (__bf16)s1; v[2] = (__bf16)s2; v[3] = (__bf16)s3;
            *(bf16x4*)&gt[j][kch][p][eb] = v;
        }
    }
    __syncthreads();

    // ---- phase 2: MFMA + epilogue ----
    const int lane = t & 63;
    const int w = t >> 6;             // wave 0..3 -> j-pair w*2, w*2+1
    const int l15 = lane & 15;
    const int kch = lane >> 4;        // 0..3
    const int pl0 = kch * 4;

    bf16x8 hfr[8];
    #pragma unroll
    for (int it = 0; it < 8; ++it)
        hfr[it] = *(const bf16x8*)(hb + ((size_t)(b * L_ + ibase + it * 16 + l15)) * A_ + kch * 8);

    bf16x8 afr[2][2];
    #pragma unroll
    for (int jj = 0; jj < 2; ++jj)
        #pragma unroll
        for (int pt = 0; pt < 2; ++pt)
            afr[jj][pt] = *(const bf16x8*)&gt[w * 2 + jj][kch][pt * 16 + l15][0];

    const f32x4 zero = {0.f, 0.f, 0.f, 0.f};

    for (int it = 0; it < 8; ++it) {
        const int i_m = ibase + it * 16 + l15;   // this lane's D column (n = i)
        #pragma unroll
        for (int jj = 0; jj < 2; ++jj) {
            const int j_l = w * 2 + jj;
            int d = i_m - (j0 + j_l);
            d = d < -8 ? -8 : (d > 8 ? 8 : d);
            d += 8;
            #pragma unroll
            for (int pt = 0; pt < 2; ++pt) {
                const f32x4 acc = __builtin_amdgcn_mfma_f32_16x16x32_bf16(afr[jj][pt], hfr[it], zero, 0, 0, 0);
                const int pl = pt * 16 + pl0;
                const f32x4 pe = *(const f32x4*)&posTl[d][pl];
                *(f32x4*)&tile[l15 * 292 + j_l * 36 + pl] = acc + pe;
            }
        }
        __syncthreads();

        {   // readout: per (i, j): 32 p's = 128B; lane covers 64B run
            const int i_loc = t >> 4;
            const int rest = t & 15;
            const int j_l = rest >> 1;
            const int half = rest & 1;
            const int i = ibase + it * 16 + i_loc;
            float* op = out + (((size_t)(b * L_ + i)) * L_ + j0 + j_l) * P_ + p0 + half * 16;
            #pragma unroll
            for (int m = 0; m < 4; ++m) {
                const f32x4 v = *(const f32x4*)&tile[i_loc * 292 + j_l * 36 + half * 16 + m * 4];
                __builtin_nontemporal_store(v, (f32x4*)(op + m * 4));
            }
        }
        __syncthreads();
    }
}

extern "C" void kernel_launch(void* const* d_in, const int* in_sizes, int n_in,
                              void* d_out, int out_size, void* d_ws, size_t ws_size,
                              hipStream_t stream) {
    const float* x     = (const float*)d_in[0];
    const float* in_w  = (const float*)d_in[1];
    const float* in_b  = (const float*)d_in[2];
    const float* out_w = (const float*)d_in[3];
    const float* out_b = (const float*)d_in[4];
    const float* pos_w = (const float*)d_in[5];
    const float* pos_b = (const float*)d_in[6];
    float* out = (float*)d_out;

    float*  hf = (float*)d_ws;                                    // 64 KB
    __bf16* hb = (__bf16*)((char*)d_ws + (size_t)B_ * L_ * A_ * 4); // +32 KB

    k1_h<<<dim3(B_ * L_ / 2), 256, 0, stream>>>(x, in_w, in_b, hf, hb);
    k2_fused<<<dim3(L_ / 8, 4, B_), 256, 0, stream>>>(hf, hb, out_w, out_b, pos_w, pos_b, out);
}